// Round 1
// baseline (235.750 us; speedup 1.0000x reference)
//
#include <hip/hip_runtime.h>

#define B_   8
#define TGT_ 256
#define SRC_ 512
#define D_   1024
#define H_   16
#define DH_  64

typedef _Float16 half4 __attribute__((ext_vector_type(4)));
typedef _Float16 half8 __attribute__((ext_vector_type(8)));
typedef float    floatx4 __attribute__((ext_vector_type(4)));

__device__ __forceinline__ void async_ld16(const void* g, void* l) {
    __builtin_amdgcn_global_load_lds(
        (const __attribute__((address_space(1))) void*)g,
        (__attribute__((address_space(3))) void*)l, 16, 0, 0);
}

// DPP move: bound_ctrl=1 -> out-of-range source lanes produce 0.0f
template <int CTRL>
__device__ __forceinline__ float dppf(float x) {
    return __int_as_float(__builtin_amdgcn_update_dpp(
        0, __float_as_int(x), CTRL, 0xF, 0xF, true));
}
__device__ __forceinline__ float rdlane(float x, int lane) {
    return __int_as_float(__builtin_amdgcn_readlane(__float_as_int(x), lane));
}

// ---------------------------------------------------------------------------
// Kernel 0: fp32 -> f16 conversion for seqs / keys / q_w / k_w (validated r2).
// ---------------------------------------------------------------------------
__global__ __launch_bounds__(256) void cvt_kernel(
    const float* __restrict__ s0, const float* __restrict__ s1,
    const float* __restrict__ s2, const float* __restrict__ s3,
    _Float16* __restrict__ d0, _Float16* __restrict__ d1,
    _Float16* __restrict__ d2, _Float16* __restrict__ d3)
{
    const int bid = blockIdx.x;
    const float* src; _Float16* dst; int base;
    if      (bid < 2048) { src = s0; dst = d0; base = bid;        }
    else if (bid < 6144) { src = s1; dst = d1; base = bid - 2048; }
    else if (bid < 7168) { src = s2; dst = d2; base = bid - 6144; }
    else                 { src = s3; dst = d3; base = bid - 7168; }
    const int idx = (base * 256 + threadIdx.x) * 4;
    float4 v = *(const float4*)(src + idx);
    half4 o = { (_Float16)v.x, (_Float16)v.y, (_Float16)v.z, (_Float16)v.w };
    *(half4*)(dst + idx) = o;
}

// ---------------------------------------------------------------------------
// Kernel 1: C = f16(relu(A @ W^T + bias)) via MFMA f16, f16 inputs.
// BM=128, BN=128, BK=32, 256 thr = 2x2 waves, wave = 64m x 64n (4x4 tiles).
// Staging via global_load_lds width=16 (m97 pattern). blocks 0-15: Q rows,
// 16-47: K rows. launch_bounds(256,2): VGPR cap 256 -> no spill (needs ~110).
// ---------------------------------------------------------------------------
__global__ __launch_bounds__(256, 2) void proj_mfma_kernel(
    const _Float16* __restrict__ seqs_h, const _Float16* __restrict__ keys_h,
    const _Float16* __restrict__ qw_h,   const _Float16* __restrict__ kw_h,
    const float* __restrict__ q_b,       const float* __restrict__ k_b,
    _Float16* __restrict__ Qh, _Float16* __restrict__ Kh)
{
    __shared__ __align__(16) _Float16 As[128 * 32];   // 8 KB
    __shared__ __align__(16) _Float16 Ws[128 * 32];   // 8 KB

    const int tid = threadIdx.x;
    const int bx  = blockIdx.x;
    const int K   = D_, N = D_;

    const _Float16* A; const _Float16* W; const float* bias; _Float16* C;
    int bm0;
    if (bx < 16) { A = seqs_h; W = qw_h; bias = q_b; C = Qh; bm0 = bx * 128; }
    else         { A = keys_h; W = kw_h; bias = k_b; C = Kh; bm0 = (bx - 16) * 128; }
    const int bn0 = blockIdx.y * 128;

    // chunk c (0..511): row c>>2, k-offset (c&3)*8 halves (16 B)
    const int c0 = tid, c1 = tid + 256;
    const _Float16* gA0 = A + (size_t)(bm0 + (c0 >> 2)) * K + (c0 & 3) * 8;
    const _Float16* gA1 = A + (size_t)(bm0 + (c1 >> 2)) * K + (c1 & 3) * 8;
    const _Float16* gW0 = W + (size_t)(bn0 + (c0 >> 2)) * K + (c0 & 3) * 8;
    const _Float16* gW1 = W + (size_t)(bn0 + (c1 >> 2)) * K + (c1 & 3) * 8;
    _Float16* lA0 = As + c0 * 8;
    _Float16* lA1 = As + c1 * 8;
    _Float16* lW0 = Ws + c0 * 8;
    _Float16* lW1 = Ws + c1 * 8;

    floatx4 acc[4][4];
#pragma unroll
    for (int i = 0; i < 4; ++i)
#pragma unroll
        for (int j = 0; j < 4; ++j) acc[i][j] = (floatx4){0.f, 0.f, 0.f, 0.f};

    const int lane = tid & 63;
    const int wid  = tid >> 6;
    const int wm   = (wid >> 1) * 64;
    const int wn   = (wid & 1) * 64;
    const int fm   = lane & 15;
    const int fk   = (lane >> 4) * 8;
    const _Float16* aF = As + (wm + fm) * 32 + fk;
    const _Float16* bF = Ws + (wn + fm) * 32 + fk;

    for (int k0 = 0; k0 < K; k0 += 32) {
        __syncthreads();                 // prev iter's ds_reads drained
        async_ld16(gA0 + k0, lA0);
        async_ld16(gA1 + k0, lA1);
        async_ld16(gW0 + k0, lW0);
        async_ld16(gW1 + k0, lW1);
        __syncthreads();                 // vmcnt(0) drain: LDS tiles ready

        half8 a[4], b[4];
#pragma unroll
        for (int i = 0; i < 4; ++i) {
            a[i] = *(const half8*)(aF + i * 16 * 32);
            b[i] = *(const half8*)(bF + i * 16 * 32);
        }
#pragma unroll
        for (int mt = 0; mt < 4; ++mt)
#pragma unroll
            for (int nt = 0; nt < 4; ++nt)
                acc[mt][nt] = __builtin_amdgcn_mfma_f32_16x16x32_f16(
                    a[mt], b[nt], acc[mt][nt], 0, 0, 0);
    }

    // epilogue: C/D layout col=lane&15, row=(lane>>4)*4+reg
    const int er = (lane >> 4) * 4;
#pragma unroll
    for (int nt = 0; nt < 4; ++nt) {
        const int col = bn0 + wn + nt * 16 + fm;
        const float bv = bias[col];
#pragma unroll
        for (int mt = 0; mt < 4; ++mt) {
            const int row0 = bm0 + wm + mt * 16 + er;
#pragma unroll
            for (int r = 0; r < 4; ++r) {
                float v = acc[mt][nt][r] + bv;
                v = fmaxf(v, 0.0f);
                C[(size_t)(row0 + r) * N + col] = (_Float16)v;
            }
        }
    }
}

// ---------------------------------------------------------------------------
// Kernel 2 (NEW, fused): energy + monotonic alignment per (b,h).
// One block per bh (128 blocks), 320 threads = 5 waves, 128 KB LDS.
//   waves 1-4 (producers): MFMA 16x512 P tile (s-range 128 each) + sigmoid
//                          -> LDS double buffer.
//   wave 0   (consumer) : DPP-scan recurrence over the current tile from LDS,
//                          coalesced float4 stores of BOTH P and Alpha.
// Eliminates the 67 MB P HBM round-trip between the old energy/align kernels
// and hides the scan's serial latency behind MFMA production.
// Scan chain + sigmoid math are verbatim from the validated kernels.
// ---------------------------------------------------------------------------
__global__ __launch_bounds__(320, 1) void energy_align_kernel(
    const _Float16* __restrict__ Q, const _Float16* __restrict__ K,
    const float* __restrict__ eb_ptr, float* __restrict__ P,
    float* __restrict__ Alpha)
{
    __shared__ __align__(16) _Float16 Kt[2 * 512 * 32];   // 64 KB [ks][row][k32]
    __shared__ __align__(16) float    Pb[2][16][512];     // 64 KB double buffer

    const int tid  = threadIdx.x;
    const int bh   = blockIdx.x;
    const int b    = bh >> 4;
    const int h    = bh & 15;
    const int lane = tid & 63;
    const int wid  = tid >> 6;

    // ---- stage K head-slice (512 x 64 f16) into Kt ----
    for (int u = tid; u < 4096; u += 320) {
        const int row = u >> 3, hc = u & 7;
        half8 v = *(const half8*)(K + ((size_t)(b * SRC_ + row)) * D_ + h * DH_ + hc * 8);
        *(half8*)(Kt + (hc >> 2) * (512 * 32) + row * 32 + (hc & 3) * 8) = v;
    }

    const float eb = eb_ptr[0];
    const int fm  = lane & 15;
    const int fk  = (lane >> 4) * 8;
    const int er  = (lane >> 4) * 4;
    const int s0w = (wid > 0) ? (wid - 1) * 128 : 0;
    const _Float16* qbase = Q + ((size_t)(b * TGT_) + fm) * D_ + h * DH_ + fk;

    float* Pg = P     + (size_t)bh * TGT_ * SRC_;
    float* Ag = Alpha + (size_t)bh * TGT_ * SRC_;
    const int n0 = lane << 3;

    // scan state (wave 0): alpha_{-1} = e_0
    float bprev[8];
#pragma unroll
    for (int j = 0; j < 8; ++j) bprev[j] = 0.0f;
    if (lane == 0) bprev[0] = 1.0f;

    auto produce = [&](int tile, int nb) {
        const _Float16* qp = qbase + (size_t)(tile * 16) * D_;
        half8 a0 = *(const half8*)(qp);        // k = fk .. fk+7        (ks=0)
        half8 a1 = *(const half8*)(qp + 32);   // k = 32+fk .. 32+fk+7  (ks=1)
        floatx4 acc[8];
#pragma unroll
        for (int nt = 0; nt < 8; ++nt) acc[nt] = (floatx4){0.f, 0.f, 0.f, 0.f};
        const _Float16* bB = Kt + (s0w + fm) * 32 + fk;
#pragma unroll
        for (int nt = 0; nt < 8; ++nt) {
            half8 b0 = *(const half8*)(bB + nt * (16 * 32));
            half8 b1 = *(const half8*)(bB + 512 * 32 + nt * (16 * 32));
            acc[nt] = __builtin_amdgcn_mfma_f32_16x16x32_f16(a0, b0, acc[nt], 0, 0, 0);
            acc[nt] = __builtin_amdgcn_mfma_f32_16x16x32_f16(a1, b1, acc[nt], 0, 0, 0);
        }
        // sigmoid epilogue -> LDS tile. C/D layout: col=lane&15, row=er+r
#pragma unroll
        for (int nt = 0; nt < 8; ++nt) {
            const int s = s0w + nt * 16 + fm;
#pragma unroll
            for (int r = 0; r < 4; ++r) {
                float x = (acc[nt][r] * 0.125f + eb) * 5.0f;
                Pb[nb][er + r][s] = 1.0f / (1.0f + __expf(-x));
            }
        }
    };

    __syncthreads();                 // Kt staged

    if (wid > 0) produce(0, 0);
    __syncthreads();                 // tile 0 ready

    for (int tile = 0; tile < 16; ++tile) {
        const int nb = tile & 1;
        if (wid > 0) {
            if (tile + 1 < 16) produce(tile + 1, nb ^ 1);
        } else {
            // ---- wave 0: scan 16 rows of this tile from LDS ----
            float4 ca = *(const float4*)&Pb[nb][0][n0];
            float4 cb = *(const float4*)&Pb[nb][0][n0 + 4];
            for (int jj = 0; jj < 16; ++jj) {
                float4 na = ca, nv = cb;
                if (jj < 15) {       // prefetch next row (hides LDS latency)
                    na = *(const float4*)&Pb[nb][jj + 1][n0];
                    nv = *(const float4*)&Pb[nb][jj + 1][n0 + 4];
                }
                float pl[8] = {ca.x, ca.y, ca.z, ca.w, cb.x, cb.y, cb.z, cb.w};

                float pm1 = dppf<0x111>(pl[7]);
                {
                    float r15 = rdlane(pl[7], 15);
                    float r31 = rdlane(pl[7], 31);
                    float r47 = rdlane(pl[7], 47);
                    pm1 = (lane == 16) ? r15 : pm1;
                    pm1 = (lane == 32) ? r31 : pm1;
                    pm1 = (lane == 48) ? r47 : pm1;
                }
                float a[8];
                a[0] = (lane == 0) ? 0.0f : (1.0f - pm1);
#pragma unroll
                for (int j = 1; j < 8; ++j) a[j] = 1.0f - pl[j - 1];

                float Aj[8], Bj[8];
                float A = a[0], Bv = bprev[0];
                Aj[0] = A; Bj[0] = Bv;
#pragma unroll
                for (int j = 1; j < 8; ++j) {
                    Bv = fmaf(a[j], Bv, bprev[j]);
                    A  = a[j] * A;
                    Aj[j] = A; Bj[j] = Bv;
                }

                float As_ = A, Bs = Bv;
                {
                    float Ash, Bsh;
                    Ash = dppf<0x111>(As_); Bsh = dppf<0x111>(Bs);
                    Ash = ((lane & 15) >= 1) ? Ash : 1.0f;
                    Bs  = fmaf(As_, Bsh, Bs); As_ = As_ * Ash;
                    Ash = dppf<0x112>(As_); Bsh = dppf<0x112>(Bs);
                    Ash = ((lane & 15) >= 2) ? Ash : 1.0f;
                    Bs  = fmaf(As_, Bsh, Bs); As_ = As_ * Ash;
                    Ash = dppf<0x114>(As_); Bsh = dppf<0x114>(Bs);
                    Ash = ((lane & 15) >= 4) ? Ash : 1.0f;
                    Bs  = fmaf(As_, Bsh, Bs); As_ = As_ * Ash;
                    Ash = dppf<0x118>(As_); Bsh = dppf<0x118>(Bs);
                    Ash = ((lane & 15) >= 8) ? Ash : 1.0f;
                    Bs  = fmaf(As_, Bsh, Bs); As_ = As_ * Ash;
                }

                float PB;
                {
                    float B15 = rdlane(Bs, 15);
                    float A31 = rdlane(As_, 31), B31 = rdlane(Bs, 31);
                    float B47 = rdlane(Bs, 47);
                    float PB1 = B15;
                    float PB2 = fmaf(A31, PB1, B31);
                    float PB3 = fmaf(rdlane(As_, 47), PB2, B47);
                    const int seg = lane >> 4;
                    PB = (seg == 0) ? 0.0f : ((seg == 1) ? PB1 : ((seg == 2) ? PB2 : PB3));
                }

                float EA = dppf<0x111>(As_);
                float EB = dppf<0x111>(Bs);
                EA = (lane & 15) ? EA : 1.0f;
                float cin = fmaf(EA, PB, EB);

                float an[8];
#pragma unroll
                for (int j = 0; j < 8; ++j) {
                    float c = fmaf(Aj[j], cin, Bj[j]);
                    an[j] = pl[j] * c;
                    bprev[j] = an[j];
                }

                const int t = tile * 16 + jj;
                float* pg = Pg + (size_t)t * SRC_ + n0;
                *(float4*)pg       = ca;            // P output (coalesced)
                *(float4*)(pg + 4) = cb;
                float4 o0 = {an[0], an[1], an[2], an[3]};
                float4 o1 = {an[4], an[5], an[6], an[7]};
                float* ag = Ag + (size_t)t * SRC_ + n0;
                *(float4*)ag       = o0;            // Alpha output
                *(float4*)(ag + 4) = o1;

                ca = na; cb = nv;
            }
        }
        __syncthreads();             // tile+1 produced / tile consumed
    }
}

// ---------------------------------------------------------------------------
extern "C" void kernel_launch(void* const* d_in, const int* in_sizes, int n_in,
                              void* d_out, int out_size, void* d_ws, size_t ws_size,
                              hipStream_t stream) {
    const float* seqs = (const float*)d_in[0];
    const float* keys = (const float*)d_in[1];
    const float* q_w  = (const float*)d_in[2];
    const float* q_b  = (const float*)d_in[3];
    const float* k_w  = (const float*)d_in[4];
    const float* k_b  = (const float*)d_in[5];
    const float* eb   = (const float*)d_in[6];

    float* out   = (float*)d_out;
    float* P     = out;
    float* Alpha = out + (size_t)B_ * H_ * TGT_ * SRC_;

    _Float16* Qh     = (_Float16*)d_ws;                   // 2048x1024 f16
    _Float16* Kh     = Qh + (size_t)B_ * TGT_ * D_;       // 4096x1024 f16
    _Float16* seqs_h = Kh + (size_t)B_ * SRC_ * D_;       // 2M
    _Float16* keys_h = seqs_h + (size_t)B_ * TGT_ * D_;   // 4M
    _Float16* qw_h   = keys_h + (size_t)B_ * SRC_ * D_;   // 1M
    _Float16* kw_h   = qw_h + (size_t)D_ * D_;            // 1M

    cvt_kernel<<<dim3(8192), 256, 0, stream>>>(seqs, keys, q_w, k_w,
                                               seqs_h, keys_h, qw_h, kw_h);
    {
        dim3 grid(48, D_ / 128);   // bx 0-15: Q (2048 rows), 16-47: K (4096)
        proj_mfma_kernel<<<grid, 256, 0, stream>>>(seqs_h, keys_h, qw_h, kw_h,
                                                   q_b, k_b, Qh, Kh);
    }
    energy_align_kernel<<<dim3(B_ * H_), 320, 0, stream>>>(Qh, Kh, eb, P, Alpha);
}

// Round 3
// 232.975 us; speedup vs baseline: 1.0119x; 1.0119x over previous
//
#include <hip/hip_runtime.h>

#define B_   8
#define TGT_ 256
#define SRC_ 512
#define D_   1024
#define H_   16
#define DH_  64

typedef _Float16 half4 __attribute__((ext_vector_type(4)));
typedef _Float16 half8 __attribute__((ext_vector_type(8)));
typedef float    floatx4 __attribute__((ext_vector_type(4)));

__device__ __forceinline__ void async_ld16(const void* g, void* l) {
    __builtin_amdgcn_global_load_lds(
        (const __attribute__((address_space(1))) void*)g,
        (__attribute__((address_space(3))) void*)l, 16, 0, 0);
}

// DPP move: bound_ctrl=1 -> out-of-range source lanes produce 0.0f
template <int CTRL>
__device__ __forceinline__ float dppf(float x) {
    return __int_as_float(__builtin_amdgcn_update_dpp(
        0, __float_as_int(x), CTRL, 0xF, 0xF, true));
}
__device__ __forceinline__ float rdlane(float x, int lane) {
    return __int_as_float(__builtin_amdgcn_readlane(__float_as_int(x), lane));
}

// ---------------------------------------------------------------------------
// Kernel 0: fp32 -> f16 conversion for seqs / keys / q_w / k_w (validated r2).
// ---------------------------------------------------------------------------
__global__ __launch_bounds__(256) void cvt_kernel(
    const float* __restrict__ s0, const float* __restrict__ s1,
    const float* __restrict__ s2, const float* __restrict__ s3,
    _Float16* __restrict__ d0, _Float16* __restrict__ d1,
    _Float16* __restrict__ d2, _Float16* __restrict__ d3)
{
    const int bid = blockIdx.x;
    const float* src; _Float16* dst; int base;
    if      (bid < 2048) { src = s0; dst = d0; base = bid;        }
    else if (bid < 6144) { src = s1; dst = d1; base = bid - 2048; }
    else if (bid < 7168) { src = s2; dst = d2; base = bid - 6144; }
    else                 { src = s3; dst = d3; base = bid - 7168; }
    const int idx = (base * 256 + threadIdx.x) * 4;
    float4 v = *(const float4*)(src + idx);
    half4 o = { (_Float16)v.x, (_Float16)v.y, (_Float16)v.z, (_Float16)v.w };
    *(half4*)(dst + idx) = o;
}

// ---------------------------------------------------------------------------
// Kernel 1: C = f16(relu(A @ W^T + bias)) via MFMA f16, f16 inputs.
// BM=128, BN=128, BK=32, 256 thr = 2x2 waves, wave = 64m x 64n (4x4 tiles).
// r2: 2-phase pipelined K-loop (T3-min recipe): double-buffered LDS,
// stage(t+1) issued BEFORE ds_read+MFMA(t), ONE barrier per iter. Removes
// the serial vmcnt(0) drain that sat inside every K-iteration before.
// ---------------------------------------------------------------------------
__global__ __launch_bounds__(256, 2) void proj_mfma_kernel(
    const _Float16* __restrict__ seqs_h, const _Float16* __restrict__ keys_h,
    const _Float16* __restrict__ qw_h,   const _Float16* __restrict__ kw_h,
    const float* __restrict__ q_b,       const float* __restrict__ k_b,
    _Float16* __restrict__ Qh, _Float16* __restrict__ Kh)
{
    __shared__ __align__(16) _Float16 As[2][128 * 32];   // 16 KB
    __shared__ __align__(16) _Float16 Ws[2][128 * 32];   // 16 KB

    const int tid = threadIdx.x;
    const int bx  = blockIdx.x;
    const int K   = D_, N = D_;

    const _Float16* A; const _Float16* W; const float* bias; _Float16* C;
    int bm0;
    if (bx < 16) { A = seqs_h; W = qw_h; bias = q_b; C = Qh; bm0 = bx * 128; }
    else         { A = keys_h; W = kw_h; bias = k_b; C = Kh; bm0 = (bx - 16) * 128; }
    const int bn0 = blockIdx.y * 128;

    // chunk c (0..511): row c>>2, k-offset (c&3)*8 halves (16 B)
    const int c0 = tid, c1 = tid + 256;
    const _Float16* gA0 = A + (size_t)(bm0 + (c0 >> 2)) * K + (c0 & 3) * 8;
    const _Float16* gA1 = A + (size_t)(bm0 + (c1 >> 2)) * K + (c1 & 3) * 8;
    const _Float16* gW0 = W + (size_t)(bn0 + (c0 >> 2)) * K + (c0 & 3) * 8;
    const _Float16* gW1 = W + (size_t)(bn0 + (c1 >> 2)) * K + (c1 & 3) * 8;

    floatx4 acc[4][4];
#pragma unroll
    for (int i = 0; i < 4; ++i)
#pragma unroll
        for (int j = 0; j < 4; ++j) acc[i][j] = (floatx4){0.f, 0.f, 0.f, 0.f};

    const int lane = tid & 63;
    const int wid  = tid >> 6;
    const int wm   = (wid >> 1) * 64;
    const int wn   = (wid & 1) * 64;
    const int fm   = lane & 15;
    const int fk   = (lane >> 4) * 8;
    const int aOff = (wm + fm) * 32 + fk;
    const int bOff = (wn + fm) * 32 + fk;

    // prologue: stage tile 0 into buffer 0
    async_ld16(gA0, &As[0][c0 * 8]);
    async_ld16(gA1, &As[0][c1 * 8]);
    async_ld16(gW0, &Ws[0][c0 * 8]);
    async_ld16(gW1, &Ws[0][c1 * 8]);
    __syncthreads();                 // compiler drains vmcnt(0): tile 0 ready

    int buf = 0;
    for (int k0 = 0; k0 < K; k0 += 32) {
        // issue next tile's staging loads FIRST (into the other buffer);
        // their latency overlaps the ds_read+MFMA below.
        if (k0 + 32 < K) {
            const int nb = buf ^ 1;
            async_ld16(gA0 + k0 + 32, &As[nb][c0 * 8]);
            async_ld16(gA1 + k0 + 32, &As[nb][c1 * 8]);
            async_ld16(gW0 + k0 + 32, &Ws[nb][c0 * 8]);
            async_ld16(gW1 + k0 + 32, &Ws[nb][c1 * 8]);
        }

        const _Float16* aF = &As[buf][aOff];
        const _Float16* bF = &Ws[buf][bOff];
        half8 a[4], b[4];
#pragma unroll
        for (int i = 0; i < 4; ++i) {
            a[i] = *(const half8*)(aF + i * 16 * 32);
            b[i] = *(const half8*)(bF + i * 16 * 32);
        }
#pragma unroll
        for (int mt = 0; mt < 4; ++mt)
#pragma unroll
            for (int nt = 0; nt < 4; ++nt)
                acc[mt][nt] = __builtin_amdgcn_mfma_f32_16x16x32_f16(
                    a[mt], b[nt], acc[mt][nt], 0, 0, 0);

        __syncthreads();   // drains prefetch residue + protects buffer reuse
        buf ^= 1;
    }

    // epilogue: C/D layout col=lane&15, row=(lane>>4)*4+reg
    const int er = (lane >> 4) * 4;
#pragma unroll
    for (int nt = 0; nt < 4; ++nt) {
        const int col = bn0 + wn + nt * 16 + fm;
        const float bv = bias[col];
#pragma unroll
        for (int mt = 0; mt < 4; ++mt) {
            const int row0 = bm0 + wm + mt * 16 + er;
#pragma unroll
            for (int r = 0; r < 4; ++r) {
                float v = acc[mt][nt][r] + bv;
                v = fmaxf(v, 0.0f);
                C[(size_t)(row0 + r) * N + col] = (_Float16)v;
            }
        }
    }
}

// ---------------------------------------------------------------------------
// Kernel 2 (fused, validated r1): energy + monotonic alignment per (b,h).
// One block per bh (128 blocks), 320 threads = 5 waves, 128 KB LDS.
//   waves 1-4 (producers): MFMA 16x512 P tile (s-range 128 each) + sigmoid
//                          -> LDS double buffer.
//   wave 0   (consumer) : DPP-scan recurrence over the current tile from LDS,
//                          coalesced float4 stores of BOTH P and Alpha.
// ---------------------------------------------------------------------------
__global__ __launch_bounds__(320, 1) void energy_align_kernel(
    const _Float16* __restrict__ Q, const _Float16* __restrict__ K,
    const float* __restrict__ eb_ptr, float* __restrict__ P,
    float* __restrict__ Alpha)
{
    __shared__ __align__(16) _Float16 Kt[2 * 512 * 32];   // 64 KB [ks][row][k32]
    __shared__ __align__(16) float    Pb[2][16][512];     // 64 KB double buffer

    const int tid  = threadIdx.x;
    const int bh   = blockIdx.x;
    const int b    = bh >> 4;
    const int h    = bh & 15;
    const int lane = tid & 63;
    const int wid  = tid >> 6;

    // ---- stage K head-slice (512 x 64 f16) into Kt ----
    for (int u = tid; u < 4096; u += 320) {
        const int row = u >> 3, hc = u & 7;
        half8 v = *(const half8*)(K + ((size_t)(b * SRC_ + row)) * D_ + h * DH_ + hc * 8);
        *(half8*)(Kt + (hc >> 2) * (512 * 32) + row * 32 + (hc & 3) * 8) = v;
    }

    const float eb = eb_ptr[0];
    const int fm  = lane & 15;
    const int fk  = (lane >> 4) * 8;
    const int er  = (lane >> 4) * 4;
    const int s0w = (wid > 0) ? (wid - 1) * 128 : 0;
    const _Float16* qbase = Q + ((size_t)(b * TGT_) + fm) * D_ + h * DH_ + fk;

    float* Pg = P     + (size_t)bh * TGT_ * SRC_;
    float* Ag = Alpha + (size_t)bh * TGT_ * SRC_;
    const int n0 = lane << 3;

    // scan state (wave 0): alpha_{-1} = e_0
    float bprev[8];
#pragma unroll
    for (int j = 0; j < 8; ++j) bprev[j] = 0.0f;
    if (lane == 0) bprev[0] = 1.0f;

    auto produce = [&](int tile, int nb) {
        const _Float16* qp = qbase + (size_t)(tile * 16) * D_;
        half8 a0 = *(const half8*)(qp);        // k = fk .. fk+7        (ks=0)
        half8 a1 = *(const half8*)(qp + 32);   // k = 32+fk .. 32+fk+7  (ks=1)
        floatx4 acc[8];
#pragma unroll
        for (int nt = 0; nt < 8; ++nt) acc[nt] = (floatx4){0.f, 0.f, 0.f, 0.f};
        const _Float16* bB = Kt + (s0w + fm) * 32 + fk;
#pragma unroll
        for (int nt = 0; nt < 8; ++nt) {
            half8 b0 = *(const half8*)(bB + nt * (16 * 32));
            half8 b1 = *(const half8*)(bB + 512 * 32 + nt * (16 * 32));
            acc[nt] = __builtin_amdgcn_mfma_f32_16x16x32_f16(a0, b0, acc[nt], 0, 0, 0);
            acc[nt] = __builtin_amdgcn_mfma_f32_16x16x32_f16(a1, b1, acc[nt], 0, 0, 0);
        }
        // sigmoid epilogue -> LDS tile. C/D layout: col=lane&15, row=er+r
#pragma unroll
        for (int nt = 0; nt < 8; ++nt) {
            const int s = s0w + nt * 16 + fm;
#pragma unroll
            for (int r = 0; r < 4; ++r) {
                float x = (acc[nt][r] * 0.125f + eb) * 5.0f;
                Pb[nb][er + r][s] = 1.0f / (1.0f + __expf(-x));
            }
        }
    };

    __syncthreads();                 // Kt staged

    if (wid > 0) produce(0, 0);
    __syncthreads();                 // tile 0 ready

    for (int tile = 0; tile < 16; ++tile) {
        const int nb = tile & 1;
        if (wid > 0) {
            if (tile + 1 < 16) produce(tile + 1, nb ^ 1);
        } else {
            // ---- wave 0: scan 16 rows of this tile from LDS ----
            float4 ca = *(const float4*)&Pb[nb][0][n0];
            float4 cb = *(const float4*)&Pb[nb][0][n0 + 4];
            for (int jj = 0; jj < 16; ++jj) {
                float4 na = ca, nv = cb;
                if (jj < 15) {       // prefetch next row (hides LDS latency)
                    na = *(const float4*)&Pb[nb][jj + 1][n0];
                    nv = *(const float4*)&Pb[nb][jj + 1][n0 + 4];
                }
                float pl[8] = {ca.x, ca.y, ca.z, ca.w, cb.x, cb.y, cb.z, cb.w};

                float pm1 = dppf<0x111>(pl[7]);
                {
                    float r15 = rdlane(pl[7], 15);
                    float r31 = rdlane(pl[7], 31);
                    float r47 = rdlane(pl[7], 47);
                    pm1 = (lane == 16) ? r15 : pm1;
                    pm1 = (lane == 32) ? r31 : pm1;
                    pm1 = (lane == 48) ? r47 : pm1;
                }
                float a[8];
                a[0] = (lane == 0) ? 0.0f : (1.0f - pm1);
#pragma unroll
                for (int j = 1; j < 8; ++j) a[j] = 1.0f - pl[j - 1];

                float Aj[8], Bj[8];
                float A = a[0], Bv = bprev[0];
                Aj[0] = A; Bj[0] = Bv;
#pragma unroll
                for (int j = 1; j < 8; ++j) {
                    Bv = fmaf(a[j], Bv, bprev[j]);
                    A  = a[j] * A;
                    Aj[j] = A; Bj[j] = Bv;
                }

                float As_ = A, Bs = Bv;
                {
                    float Ash, Bsh;
                    Ash = dppf<0x111>(As_); Bsh = dppf<0x111>(Bs);
                    Ash = ((lane & 15) >= 1) ? Ash : 1.0f;
                    Bs  = fmaf(As_, Bsh, Bs); As_ = As_ * Ash;
                    Ash = dppf<0x112>(As_); Bsh = dppf<0x112>(Bs);
                    Ash = ((lane & 15) >= 2) ? Ash : 1.0f;
                    Bs  = fmaf(As_, Bsh, Bs); As_ = As_ * Ash;
                    Ash = dppf<0x114>(As_); Bsh = dppf<0x114>(Bs);
                    Ash = ((lane & 15) >= 4) ? Ash : 1.0f;
                    Bs  = fmaf(As_, Bsh, Bs); As_ = As_ * Ash;
                    Ash = dppf<0x118>(As_); Bsh = dppf<0x118>(Bs);
                    Ash = ((lane & 15) >= 8) ? Ash : 1.0f;
                    Bs  = fmaf(As_, Bsh, Bs); As_ = As_ * Ash;
                }

                float PB;
                {
                    float B15 = rdlane(Bs, 15);
                    float A31 = rdlane(As_, 31), B31 = rdlane(Bs, 31);
                    float B47 = rdlane(Bs, 47);
                    float PB1 = B15;
                    float PB2 = fmaf(A31, PB1, B31);
                    float PB3 = fmaf(rdlane(As_, 47), PB2, B47);
                    const int seg = lane >> 4;
                    PB = (seg == 0) ? 0.0f : ((seg == 1) ? PB1 : ((seg == 2) ? PB2 : PB3));
                }

                float EA = dppf<0x111>(As_);
                float EB = dppf<0x111>(Bs);
                EA = (lane & 15) ? EA : 1.0f;
                float cin = fmaf(EA, PB, EB);

                float an[8];
#pragma unroll
                for (int j = 0; j < 8; ++j) {
                    float c = fmaf(Aj[j], cin, Bj[j]);
                    an[j] = pl[j] * c;
                    bprev[j] = an[j];
                }

                const int t = tile * 16 + jj;
                float* pg = Pg + (size_t)t * SRC_ + n0;
                *(float4*)pg       = ca;            // P output (coalesced)
                *(float4*)(pg + 4) = cb;
                float4 o0 = {an[0], an[1], an[2], an[3]};
                float4 o1 = {an[4], an[5], an[6], an[7]};
                float* ag = Ag + (size_t)t * SRC_ + n0;
                *(float4*)ag       = o0;            // Alpha output
                *(float4*)(ag + 4) = o1;

                ca = na; cb = nv;
            }
        }
        __syncthreads();             // tile+1 produced / tile consumed
    }
}

// ---------------------------------------------------------------------------
extern "C" void kernel_launch(void* const* d_in, const int* in_sizes, int n_in,
                              void* d_out, int out_size, void* d_ws, size_t ws_size,
                              hipStream_t stream) {
    const float* seqs = (const float*)d_in[0];
    const float* keys = (const float*)d_in[1];
    const float* q_w  = (const float*)d_in[2];
    const float* q_b  = (const float*)d_in[3];
    const float* k_w  = (const float*)d_in[4];
    const float* k_b  = (const float*)d_in[5];
    const float* eb   = (const float*)d_in[6];

    float* out   = (float*)d_out;
    float* P     = out;
    float* Alpha = out + (size_t)B_ * H_ * TGT_ * SRC_;

    _Float16* Qh     = (_Float16*)d_ws;                   // 2048x1024 f16
    _Float16* Kh     = Qh + (size_t)B_ * TGT_ * D_;       // 4096x1024 f16
    _Float16* seqs_h = Kh + (size_t)B_ * SRC_ * D_;       // 2M
    _Float16* keys_h = seqs_h + (size_t)B_ * TGT_ * D_;   // 4M
    _Float16* qw_h   = keys_h + (size_t)B_ * SRC_ * D_;   // 1M
    _Float16* kw_h   = qw_h + (size_t)D_ * D_;            // 1M

    cvt_kernel<<<dim3(8192), 256, 0, stream>>>(seqs, keys, q_w, k_w,
                                               seqs_h, keys_h, qw_h, kw_h);
    {
        dim3 grid(48, D_ / 128);   // bx 0-15: Q (2048 rows), 16-47: K (4096)
        proj_mfma_kernel<<<grid, 256, 0, stream>>>(seqs_h, keys_h, qw_h, kw_h,
                                                   q_b, k_b, Qh, Kh);
    }
    energy_align_kernel<<<dim3(B_ * H_), 320, 0, stream>>>(Qh, Kh, eb, P, Alpha);
}